// Round 4
// baseline (437.151 us; speedup 1.0000x reference)
//
#include <hip/hip_runtime.h>

// Problem constants (reference: S=Q=4096, E=D=2048, all fp32 in/out)
#define S_SEQ 4096
#define Q_SEQ 4096
#define E_DIM 2048
#define D_DIM 2048

typedef __bf16 bf16;
typedef __bf16 bf16x4 __attribute__((ext_vector_type(4)));
typedef __bf16 bf16x8 __attribute__((ext_vector_type(8)));
typedef float f32x4 __attribute__((ext_vector_type(4)));

// ---------------------------------------------------------------------------
// merged cast: 6 segments fp32 -> bf16 (blockIdx.y selects).
// ---------------------------------------------------------------------------
__global__ __launch_bounds__(256) void cast6(
    const float* __restrict__ i0, const float* __restrict__ i1,
    const float* __restrict__ i2, const float* __restrict__ i3,
    const float* __restrict__ i4, const float* __restrict__ i5,
    bf16* __restrict__ o0, bf16* __restrict__ o1, bf16* __restrict__ o2,
    bf16* __restrict__ o3, bf16* __restrict__ o4, bf16* __restrict__ o5) {
  const float* in;
  bf16* out;
  int n4;
  switch (blockIdx.y) {
    case 0: in = i0; out = o0; n4 = (S_SEQ * E_DIM) / 4; break;
    case 1: in = i1; out = o1; n4 = (S_SEQ * E_DIM) / 4; break;
    case 2: in = i2; out = o2; n4 = (S_SEQ * E_DIM) / 4; break;
    case 3: in = i3; out = o3; n4 = (D_DIM * E_DIM) / 4; break;
    case 4: in = i4; out = o4; n4 = (D_DIM * E_DIM) / 4; break;
    default: in = i5; out = o5; n4 = (D_DIM * E_DIM) / 4; break;
  }
  int i = blockIdx.x * 256 + threadIdx.x;
  if (i < n4) {
    float4 v = reinterpret_cast<const float4*>(in)[i];
    bf16x4 o;
    o[0] = (bf16)v.x; o[1] = (bf16)v.y; o[2] = (bf16)v.z; o[3] = (bf16)v.w;
    *reinterpret_cast<bf16x4*>(out + 4 * (size_t)i) = o;
  }
}

// ---------------------------------------------------------------------------
// async global->LDS 16B (wave-uniform lds base + lane*16 scatter)
// ---------------------------------------------------------------------------
__device__ __forceinline__ void async_copy16(const bf16* g, bf16* l) {
  __builtin_amdgcn_global_load_lds(
      (const __attribute__((address_space(1))) void*)g,
      (__attribute__((address_space(3))) void*)l, 16, 0, 0);
}

// ---------------------------------------------------------------------------
// XCD-aware tile remap (r1 version, mt=32: M=4096, BM=128). xcd = id % 8.
// Region per XCD: 8 m-tiles x (nt/2) n-tiles in a 4 (m) x 2 (n) XCD grid.
// ---------------------------------------------------------------------------
__device__ __forceinline__ void xcd_remap(int id, int nt, int& m, int& n) {
  int xcd = id & 7;
  int lid = id >> 3;
  m = (xcd & 3) * 8 + (lid & 7);
  n = (xcd >> 2) * (nt >> 1) + (lid >> 3);
}

// ---------------------------------------------------------------------------
// GEMM body: C[M,N] = A[M,K] @ B[N,K]^T, block tile 128x128, BK=64, 4 waves
// (2x2), wave tile 64x64 (acc 4x4 of mfma_f32_16x16x32_bf16).
//
// r3->r4 change (T3 "minimum 2-phase" recipe): LDS double-buffer (64 KB,
// still 2 blocks/CU) + stage-next-tile EARLY (before this tile's compute),
// drain LATE (single __syncthreads per K-tile, after compute). r1 drained
// vmcnt(0) BEFORE compute, exposing full global-load latency every K-tile
// (MfmaUtil capped at 44.8%). Now the 8 staging loads fly under ~1000 cyc of
// ds_read+MFMA, so the end-of-tile drain is nearly free. __syncthreads (not
// raw s_barrier) is deliberate: we want vmcnt(0) at exactly this point, and
// it gives compiler-safe ordering (no hoist-past-barrier races).
//
// Hazards (hand-verified): stage(t+1) writes buf[~t], last read at iter t-1,
// published safe by iter t-1's syncthreads. Reads at iter t of buf[t&1]
// staged at t-1, drained+published by t-1's syncthreads. ds_read->MFMA deps
// ordered by compiler-inserted lgkmcnt.
//
// Row stride 128B == 32 banks; the 8 16B-chunks per row are stored
// XOR-permuted (slot = kchunk ^ (row&7)) -> SQ_LDS_BANK_CONFLICT == 0 (r1).
// Staging slot ORDER untouched (global_load_lds lane-contiguity preserved).
// Epilogue modes:
//   EPI=0: bf16 out, + bias[col]                (projections)
//   EPI=1: bf16 out, exp(acc*scale)             (QK -> unnormalized E)
//   EPI=2: f32 out,  acc * aux[row]             (PV, row-normalize by 1/sum)
// ---------------------------------------------------------------------------
template <int EPI>
__device__ __forceinline__ void gemm_body(
    const bf16* __restrict__ A, int lda,
    const bf16* __restrict__ B, int ldb,
    void* __restrict__ C, int ldc,
    const float* __restrict__ aux, float scale, int K, int mBase, int nBase) {
  __shared__ __align__(16) bf16 Als[2][128 * 64];   // 2 x 16 KB
  __shared__ __align__(16) bf16 Bls[2][128 * 64];   // 2 x 16 KB

  const int tid  = threadIdx.x;
  const int wave = tid >> 6;
  const int lane = tid & 63;
  const int quad = lane >> 4;   // 0..3
  const int lrow = lane & 15;   // 0..15
  const int wRow = (wave >> 1) * 64;
  const int wCol = (wave & 1) * 64;

  f32x4 acc[4][4];
#pragma unroll
  for (int i = 0; i < 4; ++i)
#pragma unroll
    for (int j = 0; j < 4; ++j) {
      f32x4 z = {0.f, 0.f, 0.f, 0.f};
      acc[i][j] = z;
    }

  // stage both 128x64 tiles (A,B) for K-offset k0 into buffer buf.
  // 1024 x 16B chunks each; 4 chunks/thread; wave-contiguous LDS dest.
  auto stage_tile = [&](int k0, int buf) {
#pragma unroll
    for (int c = 0; c < 4; ++c) {
      int chunk = c * 256 + tid;
      int row = chunk >> 3;
      int kc = (chunk & 7) ^ (row & 7);   // swizzled k-chunk for this slot
      const bf16* g = A + (size_t)(mBase + row) * lda + k0 + kc * 8;
      async_copy16(g, &Als[buf][(size_t)(c * 256 + wave * 64) * 8]);
    }
#pragma unroll
    for (int c = 0; c < 4; ++c) {
      int chunk = c * 256 + tid;
      int row = chunk >> 3;
      int kc = (chunk & 7) ^ (row & 7);
      const bf16* g = B + (size_t)(nBase + row) * ldb + k0 + kc * 8;
      async_copy16(g, &Bls[buf][(size_t)(c * 256 + wave * 64) * 8]);
    }
  };

  // prologue: tile 0 -> buf0 (latency exposed once)
  stage_tile(0, 0);
  __syncthreads();

  const int T = K >> 6;
#pragma unroll 1
  for (int t = 0; t < T; ++t) {
    const int cur = t & 1;
    if (t + 1 < T) stage_tile((t + 1) << 6, cur ^ 1);  // issue early

#pragma unroll
    for (int kk = 0; kk < 2; ++kk) {
      bf16x8 af[4], bfr[4];
#pragma unroll
      for (int i = 0; i < 4; ++i) {
        int r = wRow + i * 16 + lrow;
        int slot = (kk * 4 + quad) ^ (r & 7);
        af[i] = *(const bf16x8*)(&Als[cur][(size_t)r * 64 + slot * 8]);
      }
#pragma unroll
      for (int j = 0; j < 4; ++j) {
        int r = wCol + j * 16 + lrow;
        int slot = (kk * 4 + quad) ^ (r & 7);
        bfr[j] = *(const bf16x8*)(&Bls[cur][(size_t)r * 64 + slot * 8]);
      }
#pragma unroll
      for (int i = 0; i < 4; ++i)
#pragma unroll
        for (int j = 0; j < 4; ++j)
          acc[i][j] = __builtin_amdgcn_mfma_f32_16x16x32_bf16(af[i], bfr[j], acc[i][j], 0, 0, 0);
    }
    __syncthreads();  // drain vmcnt(0) (stages overlapped w/ compute) + publish
  }

  // epilogue. C/D layout (verified m89/m91): col=lane&15, row=quad*4+reg
  float rinv[4][4];
  if (EPI == 2) {
#pragma unroll
    for (int i = 0; i < 4; ++i)
#pragma unroll
      for (int r = 0; r < 4; ++r)
        rinv[i][r] = aux[mBase + wRow + i * 16 + quad * 4 + r];
  }
#pragma unroll
  for (int j = 0; j < 4; ++j) {
    const int cn = nBase + wCol + j * 16 + lrow;
    float bj = 0.f;
    if (EPI == 0) bj = aux[cn];
#pragma unroll
    for (int i = 0; i < 4; ++i) {
      const int rbase = mBase + wRow + i * 16 + quad * 4;
#pragma unroll
      for (int r = 0; r < 4; ++r) {
        if (EPI == 0)
          ((bf16*)C)[(size_t)(rbase + r) * ldc + cn] = (bf16)(acc[i][j][r] + bj);
        else if (EPI == 1)
          ((bf16*)C)[(size_t)(rbase + r) * ldc + cn] =
              (bf16)__expf(acc[i][j][r] * scale);
        else
          ((float*)C)[(size_t)(rbase + r) * ldc + cn] = acc[i][j][r] * rinv[i][r];
      }
    }
  }
}

// QK: E = exp(q@k^T * scale), bf16 out
__global__ __launch_bounds__(256, 2) void qk_gemm(
    const bf16* __restrict__ A, const bf16* __restrict__ B,
    bf16* __restrict__ E, float scale) {
  int m, n;
  xcd_remap(blockIdx.x, 32, m, n);
  gemm_body<1>(A, D_DIM, B, D_DIM, (void*)E, S_SEQ, nullptr, scale, D_DIM,
               m * 128, n * 128);
}

// PV: out = (E @ vT^T) * inv[row], fp32 out
__global__ __launch_bounds__(256, 2) void pv_gemm(
    const bf16* __restrict__ E, const bf16* __restrict__ vT,
    float* __restrict__ out, const float* __restrict__ inv) {
  int m, n;
  xcd_remap(blockIdx.x, 16, m, n);
  gemm_body<2>(E, S_SEQ, vT, S_SEQ, (void*)out, D_DIM, inv, 0.f, S_SEQ,
               m * 128, n * 128);
}

// merged projections: z selects (x, W, b, out); out bf16 with bias
__global__ __launch_bounds__(256, 2) void proj_gemm(
    const bf16* __restrict__ xk, const bf16* __restrict__ xq,
    const bf16* __restrict__ xv,
    const bf16* __restrict__ Wk, const bf16* __restrict__ Wq,
    const bf16* __restrict__ Wv,
    const float* __restrict__ bk, const float* __restrict__ bq,
    const float* __restrict__ bv,
    bf16* __restrict__ ok, bf16* __restrict__ oq, bf16* __restrict__ ov) {
  const bf16 *A, *W;
  const float* b;
  bf16* o;
  switch (blockIdx.z) {
    case 0: A = xk; W = Wk; b = bk; o = ok; break;
    case 1: A = xq; W = Wq; b = bq; o = oq; break;
    default: A = xv; W = Wv; b = bv; o = ov; break;
  }
  int m, n;
  xcd_remap(blockIdx.x, 16, m, n);
  gemm_body<0>(A, E_DIM, W, E_DIM, (void*)o, D_DIM, b, 0.f, E_DIM,
               m * 128, n * 128);
}

// ---------------------------------------------------------------------------
// bf16 transpose: in[S,D] -> out[D,S], 64x64 tiles via LDS
// ---------------------------------------------------------------------------
__global__ __launch_bounds__(256) void transpose_bf16(
    const bf16* __restrict__ in, bf16* __restrict__ out) {
  __shared__ bf16 tile[64][66];
  const int t = threadIdx.x;
  const int c0 = blockIdx.x * 64;  // over D
  const int r0 = blockIdx.y * 64;  // over S
  const int col = t & 63;
  const int r4 = t >> 6;
#pragma unroll
  for (int i = 0; i < 16; ++i) {
    int rr = i * 4 + r4;
    tile[rr][col] = in[(size_t)(r0 + rr) * D_DIM + c0 + col];
  }
  __syncthreads();
#pragma unroll
  for (int i = 0; i < 16; ++i) {
    int rr = i * 4 + r4;
    out[(size_t)(c0 + rr) * S_SEQ + r0 + col] = tile[col][rr];
  }
}

// ---------------------------------------------------------------------------
// rowsum_inv: inv[r] = 1 / sum(E[r, :]). One wave per row, 4 rows per block.
// ---------------------------------------------------------------------------
__global__ __launch_bounds__(256) void rowsum_inv(
    const bf16* __restrict__ E, float* __restrict__ inv) {
  const int t = threadIdx.x;
  const int wave = t >> 6;
  const int lane = t & 63;
  const int row = blockIdx.x * 4 + wave;
  const bf16x8* src = (const bf16x8*)(E + (size_t)row * S_SEQ);
  float s = 0.f;
#pragma unroll
  for (int i = 0; i < 8; ++i) {
    bf16x8 v = src[lane + i * 64];
#pragma unroll
    for (int j = 0; j < 8; ++j) s += (float)v[j];
  }
#pragma unroll
  for (int off = 32; off > 0; off >>= 1)
    s += __shfl_down(s, off, 64);
  if (lane == 0) inv[row] = 1.0f / s;
}

// ---------------------------------------------------------------------------
// launcher
// ---------------------------------------------------------------------------
extern "C" void kernel_launch(void* const* d_in, const int* in_sizes, int n_in,
                              void* d_out, int out_size, void* d_ws, size_t ws_size,
                              hipStream_t stream) {
  const float* key   = (const float*)d_in[0];
  const float* value = (const float*)d_in[1];
  const float* query = (const float*)d_in[2];
  const float* Wk = (const float*)d_in[3];
  const float* bk = (const float*)d_in[4];
  const float* Wq = (const float*)d_in[5];
  const float* bq = (const float*)d_in[6];
  const float* Wv = (const float*)d_in[7];
  const float* bv = (const float*)d_in[8];

  const size_t MB = 1ull << 20;
  char* ws = (char*)d_ws;
  bf16* key_bf   = (bf16*)(ws + 0 * MB);
  bf16* value_bf = (bf16*)(ws + 16 * MB);
  bf16* query_bf = (bf16*)(ws + 32 * MB);
  bf16* Wk_bf    = (bf16*)(ws + 48 * MB);
  bf16* Wq_bf    = (bf16*)(ws + 56 * MB);
  bf16* Wv_bf    = (bf16*)(ws + 64 * MB);
  bf16* k_bf     = (bf16*)(ws + 72 * MB);
  bf16* q_bf     = (bf16*)(ws + 88 * MB);
  bf16* v_bf     = (bf16*)(ws + 104 * MB);
  bf16* vT_bf    = (bf16*)(ws + 120 * MB);
  bf16* E        = (bf16*)(ws + 0 * MB);
  float* inv     = (float*)(ws + 34 * MB);

  dim3 blk(256);

  // 1. all six casts in one dispatch
  cast6<<<dim3(8192, 6), blk, 0, stream>>>(
      key, value, query, Wk, Wq, Wv,
      key_bf, value_bf, query_bf, Wk_bf, Wq_bf, Wv_bf);

  // 2. projections: M=4096 (32 tiles), N=2048 (16 tiles) -> 512 blocks/slice
  proj_gemm<<<dim3(512, 1, 3), blk, 0, stream>>>(
      key_bf, query_bf, value_bf, Wk_bf, Wq_bf, Wv_bf, bk, bq, bv,
      k_bf, q_bf, v_bf);

  // 3. v^T for the PV GEMM
  transpose_bf16<<<dim3(D_DIM / 64, S_SEQ / 64), blk, 0, stream>>>(v_bf, vT_bf);

  // 4. E = exp(q @ k^T * scale), bf16
  const float scale = 0.022097086912079608f;  // 1/sqrt(2048)
  qk_gemm<<<dim3(1024), blk, 0, stream>>>(q_bf, k_bf, E, scale);

  // 5. inv[r] = 1/rowsum(E)
  rowsum_inv<<<dim3(1024), blk, 0, stream>>>(E, inv);

  // 6. out = (E @ v) * inv[row], fp32 to d_out; 32 m x 16 n = 512 blocks
  pv_gemm<<<dim3(512), blk, 0, stream>>>(E, vT_bf, (float*)d_out, inv);
}

// Round 6
// 416.042 us; speedup vs baseline: 1.0507x; 1.0507x over previous
//
#include <hip/hip_runtime.h>

// Problem constants (reference: S=Q=4096, E=D=2048, all fp32 in/out)
#define S_SEQ 4096
#define Q_SEQ 4096
#define E_DIM 2048
#define D_DIM 2048

typedef __bf16 bf16;
typedef __bf16 bf16x4 __attribute__((ext_vector_type(4)));
typedef __bf16 bf16x8 __attribute__((ext_vector_type(8)));
typedef float f32x4 __attribute__((ext_vector_type(4)));

// ---------------------------------------------------------------------------
// merged cast: 6 segments fp32 -> bf16 (blockIdx.y selects).
// ---------------------------------------------------------------------------
__global__ __launch_bounds__(256) void cast6(
    const float* __restrict__ i0, const float* __restrict__ i1,
    const float* __restrict__ i2, const float* __restrict__ i3,
    const float* __restrict__ i4, const float* __restrict__ i5,
    bf16* __restrict__ o0, bf16* __restrict__ o1, bf16* __restrict__ o2,
    bf16* __restrict__ o3, bf16* __restrict__ o4, bf16* __restrict__ o5) {
  const float* in;
  bf16* out;
  int n4;
  switch (blockIdx.y) {
    case 0: in = i0; out = o0; n4 = (S_SEQ * E_DIM) / 4; break;
    case 1: in = i1; out = o1; n4 = (S_SEQ * E_DIM) / 4; break;
    case 2: in = i2; out = o2; n4 = (S_SEQ * E_DIM) / 4; break;
    case 3: in = i3; out = o3; n4 = (D_DIM * E_DIM) / 4; break;
    case 4: in = i4; out = o4; n4 = (D_DIM * E_DIM) / 4; break;
    default: in = i5; out = o5; n4 = (D_DIM * E_DIM) / 4; break;
  }
  int i = blockIdx.x * 256 + threadIdx.x;
  if (i < n4) {
    float4 v = reinterpret_cast<const float4*>(in)[i];
    bf16x4 o;
    o[0] = (bf16)v.x; o[1] = (bf16)v.y; o[2] = (bf16)v.z; o[3] = (bf16)v.w;
    *reinterpret_cast<bf16x4*>(out + 4 * (size_t)i) = o;
  }
}

// ---------------------------------------------------------------------------
// async global->LDS 16B (wave-uniform lds base + lane*16 scatter)
// ---------------------------------------------------------------------------
__device__ __forceinline__ void async_copy16(const bf16* g, bf16* l) {
  __builtin_amdgcn_global_load_lds(
      (const __attribute__((address_space(1))) void*)g,
      (__attribute__((address_space(3))) void*)l, 16, 0, 0);
}

// ---------------------------------------------------------------------------
// XCD-aware tile remaps. Both bijective; 4(m) x 2(n) XCD grid.
// remap32: m-tiles of 128 (mt=32).  remap16: m-tiles of 256 (mt=16).
// ---------------------------------------------------------------------------
__device__ __forceinline__ void xcd_remap32(int id, int nt, int& m, int& n) {
  int xcd = id & 7;
  int lid = id >> 3;
  m = (xcd & 3) * 8 + (lid & 7);
  n = (xcd >> 2) * (nt >> 1) + (lid >> 3);
}
__device__ __forceinline__ void xcd_remap16(int id, int nt, int& m, int& n) {
  int xcd = id & 7;
  int lid = id >> 3;
  m = (xcd & 3) * 4 + (lid & 3);
  n = (xcd >> 2) * (nt >> 1) + (lid >> 2);
}

// ===========================================================================
// BODY A (r1 champion, proj): single-buffer 128x128, BK=64, 4 waves (2x2),
// wave tile 64x64. 32 KB LDS -> ~2.6 blocks/CU; latency hiding via implicit
// multi-block overlap (m114). Verified 103 us / MfmaUtil 44.8% on proj (r1).
// Explicit pipelining attempts (r2 8ph, r3 4ph, r4 dbuf) all LOST to this by
// cutting co-residency — do not re-attempt without template-exact geometry.
// Row stride 128B == 32 banks; 16B chunks XOR-permuted (slot = kc ^ (row&7))
// -> SQ_LDS_BANK_CONFLICT == 0. Epilogue EPI=0: bf16 out + bias[col].
// ===========================================================================
template <int EPI>
__device__ __forceinline__ void gemm_body_sb(
    const bf16* __restrict__ A, int lda,
    const bf16* __restrict__ B, int ldb,
    void* __restrict__ C, int ldc,
    const float* __restrict__ aux, float scale, int K, int mBase, int nBase) {
  __shared__ __align__(16) bf16 Als[128 * 64];   // 16 KB
  __shared__ __align__(16) bf16 Bls[128 * 64];   // 16 KB

  const int tid  = threadIdx.x;
  const int wave = tid >> 6;
  const int lane = tid & 63;
  const int quad = lane >> 4;   // 0..3
  const int lrow = lane & 15;   // 0..15
  const int wRow = (wave >> 1) * 64;
  const int wCol = (wave & 1) * 64;

  f32x4 acc[4][4];
#pragma unroll
  for (int i = 0; i < 4; ++i)
#pragma unroll
    for (int j = 0; j < 4; ++j) {
      f32x4 z = {0.f, 0.f, 0.f, 0.f};
      acc[i][j] = z;
    }

  for (int k0 = 0; k0 < K; k0 += 64) {
#pragma unroll
    for (int c = 0; c < 4; ++c) {
      int chunk = c * 256 + tid;
      int row = chunk >> 3;
      int kc = (chunk & 7) ^ (row & 7);
      const bf16* g = A + (size_t)(mBase + row) * lda + k0 + kc * 8;
      async_copy16(g, Als + (size_t)(c * 256 + wave * 64) * 8);
    }
#pragma unroll
    for (int c = 0; c < 4; ++c) {
      int chunk = c * 256 + tid;
      int row = chunk >> 3;
      int kc = (chunk & 7) ^ (row & 7);
      const bf16* g = B + (size_t)(nBase + row) * ldb + k0 + kc * 8;
      async_copy16(g, Bls + (size_t)(c * 256 + wave * 64) * 8);
    }
    __syncthreads();  // drains vmcnt: LDS tiles ready

#pragma unroll
    for (int kk = 0; kk < 2; ++kk) {
      bf16x8 af[4], bfr[4];
#pragma unroll
      for (int i = 0; i < 4; ++i) {
        int r = wRow + i * 16 + lrow;
        int slot = (kk * 4 + quad) ^ (r & 7);
        af[i] = *(const bf16x8*)(Als + (size_t)r * 64 + slot * 8);
      }
#pragma unroll
      for (int j = 0; j < 4; ++j) {
        int r = wCol + j * 16 + lrow;
        int slot = (kk * 4 + quad) ^ (r & 7);
        bfr[j] = *(const bf16x8*)(Bls + (size_t)r * 64 + slot * 8);
      }
#pragma unroll
      for (int i = 0; i < 4; ++i)
#pragma unroll
        for (int j = 0; j < 4; ++j)
          acc[i][j] = __builtin_amdgcn_mfma_f32_16x16x32_bf16(af[i], bfr[j], acc[i][j], 0, 0, 0);
    }
    __syncthreads();  // compute done; safe to overwrite LDS next iter
  }

  // epilogue. C/D layout (verified m89/m91): col=lane&15, row=quad*4+reg
  float rinv[4][4];
  if (EPI == 2) {
#pragma unroll
    for (int i = 0; i < 4; ++i)
#pragma unroll
      for (int r = 0; r < 4; ++r)
        rinv[i][r] = aux[mBase + wRow + i * 16 + quad * 4 + r];
  }
#pragma unroll
  for (int j = 0; j < 4; ++j) {
    const int cn = nBase + wCol + j * 16 + lrow;
    float bj = 0.f;
    if (EPI == 0) bj = aux[cn];
#pragma unroll
    for (int i = 0; i < 4; ++i) {
      const int rbase = mBase + wRow + i * 16 + quad * 4;
#pragma unroll
      for (int r = 0; r < 4; ++r) {
        if (EPI == 0)
          ((bf16*)C)[(size_t)(rbase + r) * ldc + cn] = (bf16)(acc[i][j][r] + bj);
        else if (EPI == 1)
          ((bf16*)C)[(size_t)(rbase + r) * ldc + cn] =
              (bf16)__expf(acc[i][j][r] * scale);
        else
          ((float*)C)[(size_t)(rbase + r) * ldc + cn] = acc[i][j][r] * rinv[i][r];
      }
    }
  }
}

// ===========================================================================
// BODY B (r3, qk/pv): 4-phase counted-vmcnt 256x128, BK=64, 8 waves (4x2),
// wave tile 64x64. 96 KB LDS -> 1 block/CU. Verified correct r3; measurably
// better than BODY A for the S=4096-output GEMMs (larger m-tile halves
// per-block A-refetch; non-proj time 325 -> 309 us r1 vs r3).
// ===========================================================================
__device__ __forceinline__ void stage_half(const bf16* __restrict__ G, int ld,
                                           int grow0, int k0, bf16* lds,
                                           int wave, int lane) {
#pragma unroll
  for (int s = 0; s < 2; ++s) {
    int c = (wave * 2 + s) * 64 + lane;  // 16B-chunk index within half, 0..1023
    int row = c >> 3;                    // 0..127 (8 chunks per 64-col row)
    int kc = (c & 7) ^ (row & 7);        // swizzled k-chunk for this slot
    const bf16* g = G + (size_t)(grow0 + row) * ld + k0 + kc * 8;
    async_copy16(g, lds + (size_t)(wave * 2 + s) * 512);
  }
}

#define BARRIER __builtin_amdgcn_s_barrier()
#define LGKM0 asm volatile("s_waitcnt lgkmcnt(0)" ::: "memory")
#define VMCNT2 asm volatile("s_waitcnt vmcnt(2)" ::: "memory")
#define VMCNT0 asm volatile("s_waitcnt vmcnt(0)" ::: "memory")

#define RD_A(buf, IP)                                                         \
  _Pragma("unroll") for (int ii = 0; ii < 2; ++ii)                            \
  _Pragma("unroll") for (int kk = 0; kk < 2; ++kk)                            \
      aR[ii][kk] = *(const bf16x8*)(&Als[buf][(size_t)(wRow + ((IP)*2 + ii) * 16 + lrow) * 64 + slotk[kk] * 8]);

#define RD_B(buf, JP, dst)                                                    \
  _Pragma("unroll") for (int jj = 0; jj < 2; ++jj)                            \
  _Pragma("unroll") for (int kk = 0; kk < 2; ++kk)                            \
      dst[jj][kk] = *(const bf16x8*)(&Bls[buf][(size_t)(wCol + ((JP)*2 + jj) * 16 + lrow) * 64 + slotk[kk] * 8]);

#define MMA16(IP)                                                              \
  __builtin_amdgcn_s_setprio(1);                                               \
  _Pragma("unroll") for (int jj = 0; jj < 2; ++jj)                             \
  _Pragma("unroll") for (int ii = 0; ii < 2; ++ii)                             \
  _Pragma("unroll") for (int kk = 0; kk < 2; ++kk)                             \
      acc[(IP)*2 + ii][jj] = __builtin_amdgcn_mfma_f32_16x16x32_bf16(          \
          aR[ii][kk], b0[jj][kk], acc[(IP)*2 + ii][jj], 0, 0, 0);              \
  _Pragma("unroll") for (int jj = 0; jj < 2; ++jj)                             \
  _Pragma("unroll") for (int ii = 0; ii < 2; ++ii)                             \
  _Pragma("unroll") for (int kk = 0; kk < 2; ++kk)                             \
      acc[(IP)*2 + ii][2 + jj] = __builtin_amdgcn_mfma_f32_16x16x32_bf16(      \
          aR[ii][kk], b1[jj][kk], acc[(IP)*2 + ii][2 + jj], 0, 0, 0);          \
  __builtin_amdgcn_s_setprio(0)

template <int EPI>
__device__ __forceinline__ void gemm_body_4ph(
    const bf16* __restrict__ A, int lda,
    const bf16* __restrict__ B, int ldb,
    void* __restrict__ C, int ldc,
    const float* __restrict__ aux, float scale, int K, int mBase, int nBase) {
  __shared__ __align__(16) bf16 Als[2][256 * 64];  // 64 KB
  __shared__ __align__(16) bf16 Bls[2][128 * 64];  // 32 KB

  const int tid  = threadIdx.x;
  const int wave = tid >> 6;   // 0..7
  const int lane = tid & 63;
  const int quad = lane >> 4;  // 0..3
  const int lrow = lane & 15;  // 0..15
  const int wRow = (wave >> 1) * 64;  // 0,64,128,192
  const int wCol = (wave & 1) * 64;   // 0,64
  const int slotk[2] = {quad ^ (lrow & 7), (4 + quad) ^ (lrow & 7)};

  f32x4 acc[4][4];
#pragma unroll
  for (int i = 0; i < 4; ++i)
#pragma unroll
    for (int j = 0; j < 4; ++j) {
      f32x4 z = {0.f, 0.f, 0.f, 0.f};
      acc[i][j] = z;
    }

  bf16x8 aR[2][2], b0[2][2], b1[2][2];

  // prologue: tile0 {B, A.lo, A.hi} + B(1). (8 loads/thread; oldest 6 = tile0)
  stage_half(B, ldb, nBase, 0, &Bls[0][0], wave, lane);               // B(0)
  stage_half(A, lda, mBase, 0, &Als[0][0], wave, lane);               // A.lo(0)
  stage_half(A, lda, mBase + 128, 0, &Als[0][128 * 64], wave, lane);  // A.hi(0)
  stage_half(B, ldb, nBase, 64, &Bls[1][0], wave, lane);              // B(1)
  VMCNT2;  // tile0's 3 halves landed
  BARRIER;

  const int NI = K >> 7;  // 2 K-tiles (128 cols of K) per iteration
#pragma unroll 1
  for (int i = 0; i < NI; ++i) {
    const bool nl = (i + 1 < NI);
    const int kb = i * 128;
    // ---- phA0 (tile e in buf0)
    RD_A(0, 0);
    RD_B(0, 0, b0);
    RD_B(0, 1, b1);
    stage_half(A, lda, mBase, kb + 64, &Als[1][0], wave, lane);            // A.lo(o)
    stage_half(A, lda, mBase + 128, kb + 64, &Als[1][128 * 64], wave, lane); // A.hi(o)
    BARRIER; LGKM0; MMA16(0); BARRIER;
    // ---- phB0
    RD_A(0, 1);
    if (nl) {
      stage_half(B, ldb, nBase, kb + 128, &Bls[0][0], wave, lane);         // B(ne)
      VMCNT2;  // tile o's 3 halves landed
    } else {
      VMCNT0;  // tail: drain tile o's 6
    }
    BARRIER; LGKM0; MMA16(1); BARRIER;
    // ---- phA1 (tile o in buf1)
    RD_A(1, 0);
    RD_B(1, 0, b0);
    RD_B(1, 1, b1);
    if (nl) {
      stage_half(A, lda, mBase, kb + 128, &Als[0][0], wave, lane);           // A.lo(ne)
      stage_half(A, lda, mBase + 128, kb + 128, &Als[0][128 * 64], wave, lane); // A.hi(ne)
    }
    BARRIER; LGKM0; MMA16(0); BARRIER;
    // ---- phB1
    RD_A(1, 1);
    if (nl) {
      stage_half(B, ldb, nBase, kb + 192, &Bls[1][0], wave, lane);         // B(no)
      VMCNT2;  // tile ne's 3 halves landed
    }
    BARRIER; LGKM0; MMA16(1); BARRIER;
  }

  // epilogue. C/D layout (verified m89/m91): col=lane&15, row=quad*4+reg
  float rinv[4][4];
  if (EPI == 2) {
#pragma unroll
    for (int i = 0; i < 4; ++i)
#pragma unroll
      for (int r = 0; r < 4; ++r)
        rinv[i][r] = aux[mBase + wRow + i * 16 + quad * 4 + r];
  }
#pragma unroll
  for (int j = 0; j < 4; ++j) {
    const int cn = nBase + wCol + j * 16 + lrow;
    float bj = 0.f;
    if (EPI == 0) bj = aux[cn];
#pragma unroll
    for (int i = 0; i < 4; ++i) {
      const int rbase = mBase + wRow + i * 16 + quad * 4;
#pragma unroll
      for (int r = 0; r < 4; ++r) {
        if (EPI == 0)
          ((bf16*)C)[(size_t)(rbase + r) * ldc + cn] = (bf16)(acc[i][j][r] + bj);
        else if (EPI == 1)
          ((bf16*)C)[(size_t)(rbase + r) * ldc + cn] =
              (bf16)__expf(acc[i][j][r] * scale);
        else
          ((float*)C)[(size_t)(rbase + r) * ldc + cn] = acc[i][j][r] * rinv[i][r];
      }
    }
  }
}

// QK: E = exp(q@k^T * scale), bf16 out. BODY B, mt=16, nt=32 -> 512 blocks.
__global__ __launch_bounds__(512, 2) void qk_gemm(
    const bf16* __restrict__ A, const bf16* __restrict__ B,
    bf16* __restrict__ E, float scale) {
  int m, n;
  xcd_remap16(blockIdx.x, 32, m, n);
  gemm_body_4ph<1>(A, D_DIM, B, D_DIM, (void*)E, S_SEQ, nullptr, scale, D_DIM,
                   m * 256, n * 128);
}

// PV: out = (E @ vT^T) * inv[row], fp32 out. BODY B, mt=16, nt=16 -> 256 blocks.
__global__ __launch_bounds__(512, 2) void pv_gemm(
    const bf16* __restrict__ E, const bf16* __restrict__ vT,
    float* __restrict__ out, const float* __restrict__ inv) {
  int m, n;
  xcd_remap16(blockIdx.x, 16, m, n);
  gemm_body_4ph<2>(E, S_SEQ, vT, S_SEQ, (void*)out, D_DIM, inv, 0.f, S_SEQ,
                   m * 256, n * 128);
}

// merged projections: BODY A (r1 champion), mt=32, nt=16 -> 512 blocks/slice.
__global__ __launch_bounds__(256, 2) void proj_gemm(
    const bf16* __restrict__ xk, const bf16* __restrict__ xq,
    const bf16* __restrict__ xv,
    const bf16* __restrict__ Wk, const bf16* __restrict__ Wq,
    const bf16* __restrict__ Wv,
    const float* __restrict__ bk, const float* __restrict__ bq,
    const float* __restrict__ bv,
    bf16* __restrict__ ok, bf16* __restrict__ oq, bf16* __restrict__ ov) {
  const bf16 *A, *W;
  const float* b;
  bf16* o;
  switch (blockIdx.z) {
    case 0: A = xk; W = Wk; b = bk; o = ok; break;
    case 1: A = xq; W = Wq; b = bq; o = oq; break;
    default: A = xv; W = Wv; b = bv; o = ov; break;
  }
  int m, n;
  xcd_remap32(blockIdx.x, 16, m, n);
  gemm_body_sb<0>(A, E_DIM, W, E_DIM, (void*)o, D_DIM, b, 0.f, E_DIM,
                  m * 128, n * 128);
}

// ---------------------------------------------------------------------------
// bf16 transpose: in[S,D] -> out[D,S], 64x64 tiles via LDS
// ---------------------------------------------------------------------------
__global__ __launch_bounds__(256) void transpose_bf16(
    const bf16* __restrict__ in, bf16* __restrict__ out) {
  __shared__ bf16 tile[64][66];
  const int t = threadIdx.x;
  const int c0 = blockIdx.x * 64;  // over D
  const int r0 = blockIdx.y * 64;  // over S
  const int col = t & 63;
  const int r4 = t >> 6;
#pragma unroll
  for (int i = 0; i < 16; ++i) {
    int rr = i * 4 + r4;
    tile[rr][col] = in[(size_t)(r0 + rr) * D_DIM + c0 + col];
  }
  __syncthreads();
#pragma unroll
  for (int i = 0; i < 16; ++i) {
    int rr = i * 4 + r4;
    out[(size_t)(c0 + rr) * S_SEQ + r0 + col] = tile[col][rr];
  }
}

// ---------------------------------------------------------------------------
// rowsum_inv: inv[r] = 1 / sum(E[r, :]). One wave per row, 4 rows per block.
// ---------------------------------------------------------------------------
__global__ __launch_bounds__(256) void rowsum_inv(
    const bf16* __restrict__ E, float* __restrict__ inv) {
  const int t = threadIdx.x;
  const int wave = t >> 6;
  const int lane = t & 63;
  const int row = blockIdx.x * 4 + wave;
  const bf16x8* src = (const bf16x8*)(E + (size_t)row * S_SEQ);
  float s = 0.f;
#pragma unroll
  for (int i = 0; i < 8; ++i) {
    bf16x8 v = src[lane + i * 64];
#pragma unroll
    for (int j = 0; j < 8; ++j) s += (float)v[j];
  }
#pragma unroll
  for (int off = 32; off > 0; off >>= 1)
    s += __shfl_down(s, off, 64);
  if (lane == 0) inv[row] = 1.0f / s;
}

// ---------------------------------------------------------------------------
// launcher
// ---------------------------------------------------------------------------
extern "C" void kernel_launch(void* const* d_in, const int* in_sizes, int n_in,
                              void* d_out, int out_size, void* d_ws, size_t ws_size,
                              hipStream_t stream) {
  const float* key   = (const float*)d_in[0];
  const float* value = (const float*)d_in[1];
  const float* query = (const float*)d_in[2];
  const float* Wk = (const float*)d_in[3];
  const float* bk = (const float*)d_in[4];
  const float* Wq = (const float*)d_in[5];
  const float* bq = (const float*)d_in[6];
  const float* Wv = (const float*)d_in[7];
  const float* bv = (const float*)d_in[8];

  const size_t MB = 1ull << 20;
  char* ws = (char*)d_ws;
  bf16* key_bf   = (bf16*)(ws + 0 * MB);
  bf16* value_bf = (bf16*)(ws + 16 * MB);
  bf16* query_bf = (bf16*)(ws + 32 * MB);
  bf16* Wk_bf    = (bf16*)(ws + 48 * MB);
  bf16* Wq_bf    = (bf16*)(ws + 56 * MB);
  bf16* Wv_bf    = (bf16*)(ws + 64 * MB);
  bf16* k_bf     = (bf16*)(ws + 72 * MB);
  bf16* q_bf     = (bf16*)(ws + 88 * MB);
  bf16* v_bf     = (bf16*)(ws + 104 * MB);
  bf16* vT_bf    = (bf16*)(ws + 120 * MB);
  bf16* E        = (bf16*)(ws + 0 * MB);
  float* inv     = (float*)(ws + 34 * MB);

  dim3 blk(256);
  dim3 blk512(512);

  // 1. all six casts in one dispatch
  cast6<<<dim3(8192, 6), blk, 0, stream>>>(
      key, value, query, Wk, Wq, Wv,
      key_bf, value_bf, query_bf, Wk_bf, Wq_bf, Wv_bf);

  // 2. projections (BODY A): M=4096 (32 tiles), N=2048 (16) -> 512 blocks/slice
  proj_gemm<<<dim3(512, 1, 3), blk, 0, stream>>>(
      key_bf, query_bf, value_bf, Wk_bf, Wq_bf, Wv_bf, bk, bq, bv,
      k_bf, q_bf, v_bf);

  // 3. v^T for the PV GEMM
  transpose_bf16<<<dim3(D_DIM / 64, S_SEQ / 64), blk, 0, stream>>>(v_bf, vT_bf);

  // 4. E = exp(q @ k^T * scale) (BODY B): 16 m x 32 n = 512 blocks
  const float scale = 0.022097086912079608f;  // 1/sqrt(2048)
  qk_gemm<<<dim3(512), blk512, 0, stream>>>(q_bf, k_bf, E, scale);

  // 5. inv[r] = 1/rowsum(E)
  rowsum_inv<<<dim3(1024), blk, 0, stream>>>(E, inv);

  // 6. out = (E @ v) * inv[row] (BODY B): 16 m x 16 n = 256 blocks
  pv_gemm<<<dim3(256), blk512, 0, stream>>>(E, vT_bf, (float*)d_out, inv);
}